// Round 1
// baseline (11126.241 us; speedup 1.0000x reference)
//
#include <hip/hip_runtime.h>
#include <hip/hip_bf16.h>

typedef __attribute__((ext_vector_type(8))) short short8;
typedef __attribute__((ext_vector_type(4))) float floatx4;

#define T_STEPS 512
#define BATCH   32
#define HDIM    1024
#define GATE4   4096
#define DA_DIM  64
#define NWG     256
#define EPS_LN  1e-5f

// round-to-nearest-even fp32 -> bf16 bit pattern
__device__ __forceinline__ unsigned short f2bf(float f) {
    unsigned u = __float_as_uint(f);
    unsigned r = (u + 0x7FFFu + ((u >> 16) & 1u)) >> 16;
    return (unsigned short)r;
}

// ---------------------------------------------------------------------------
// W fragment prep: wf[w][kb][lane][j]  (A-operand layout, K = [x(1024);h(1024)])
// m = lane&15 -> row = (m>>2)*1024 + w*4 + (m&3);  k = kb*32 + (lane>>4)*8 + j
// ---------------------------------------------------------------------------
__global__ void __launch_bounds__(256) prep_wfrag(
    const float* __restrict__ Wih, const float* __restrict__ Whh,
    unsigned short* __restrict__ wf)
{
    int gid = blockIdx.x * 256 + threadIdx.x;   // 256*64*64 = 1,048,576
    int lane = gid & 63;
    int kb   = (gid >> 6) & 63;
    int w    = gid >> 12;
    int m    = lane & 15;
    int row  = (m >> 2) * HDIM + w * 4 + (m & 3);
    int k0   = kb * 32 + (lane >> 4) * 8;
    const float* src = (k0 < HDIM) ? (Wih + (size_t)row * HDIM + k0)
                                   : (Whh + (size_t)row * HDIM + (k0 - HDIM));
    unsigned short* dst = wf + (size_t)gid * 8;
#pragma unroll
    for (int j = 0; j < 8; ++j) dst[j] = f2bf(src[j]);
}

// ---------------------------------------------------------------------------
// x fragment prep: per t, xf[t][kb][nb][lane][j]  (B-operand layout)
// n = nb*16 + (lane&15) = batch;  k = kb*32 + (lane>>4)*8 + j
// ---------------------------------------------------------------------------
__global__ void __launch_bounds__(256) prep_xfrag(
    const float* __restrict__ x, unsigned short* __restrict__ xf)
{
    int gid = blockIdx.x * 256 + threadIdx.x;   // 512*32*2*64 = 2,097,152
    int lane = gid & 63;
    int nb   = (gid >> 6) & 1;
    int kb   = (gid >> 7) & 31;
    int t    = gid >> 12;
    int b    = nb * 16 + (lane & 15);
    int k0   = kb * 32 + (lane >> 4) * 8;
    const float* src = x + ((size_t)(t * BATCH + b)) * HDIM + k0;
    unsigned short* dst = xf + (size_t)t * 32768 + (((kb * 2 + nb) * 64 + lane) * 8);
#pragma unroll
    for (int j = 0; j < 8; ++j) dst[j] = f2bf(src[j]);
}

// ---------------------------------------------------------------------------
// One LSTM timestep. Grid 256 WGs x 256 thr. WG w owns h-dims [w*4, w*4+4)
// (16 gate rows). Fused input projection: K = 2048 over [x_t ; h_{t-1}].
// 4 waves K-split (16 kb each), LDS reduce, gates, c/h update.
// ---------------------------------------------------------------------------
__global__ void __launch_bounds__(256) lstm_step(
    int t,
    const unsigned short* __restrict__ xf,
    const unsigned short* __restrict__ wf,
    unsigned short* __restrict__ hfrag,      // 2 buffers x 32768 elems
    const float* __restrict__ bih, const float* __restrict__ bhh,
    float* __restrict__ cbuf,                // [B][H]
    float* __restrict__ hs)                  // [T][B][H]
{
    __shared__ float part[8 * 256];          // [wave][nb][m][n]
    __shared__ float gates[16 * 32];         // [m][batch]
    int tid  = threadIdx.x;
    int w    = blockIdx.x;
    int lane = tid & 63;
    int v    = tid >> 6;

    const unsigned short* hb    = hfrag + (size_t)(t & 1) * 32768;
    const unsigned short* xbase = xf + (size_t)t * 32768;
    const unsigned short* wbase = wf + (size_t)w * 32768;

    floatx4 acc0 = {0.f, 0.f, 0.f, 0.f};
    floatx4 acc1 = {0.f, 0.f, 0.f, 0.f};

#pragma unroll 4
    for (int i = 0; i < 16; ++i) {
        int kb = v * 16 + i;
        short8 a = *(const short8*)(wbase + ((size_t)(kb * 64 + lane) * 8));
        const unsigned short* ub = (kb < 32)
            ? (xbase + ((size_t)((kb * 2) * 64 + lane) * 8))
            : (hb + ((size_t)(((kb - 32) * 2) * 64 + lane) * 8));
        short8 b0 = *(const short8*)(ub);
        short8 b1 = *(const short8*)(ub + 512);   // nb=1 block (+64*8 elems)
        acc0 = __builtin_amdgcn_mfma_f32_16x16x32_bf16(a, b0, acc0, 0, 0, 0);
        acc1 = __builtin_amdgcn_mfma_f32_16x16x32_bf16(a, b1, acc1, 0, 0, 0);
    }
    {
        int n = lane & 15, q = lane >> 4;
#pragma unroll
        for (int r = 0; r < 4; ++r) {
            int m = q * 4 + r;
            part[(v * 2 + 0) * 256 + m * 16 + n] = acc0[r];
            part[(v * 2 + 1) * 256 + m * 16 + n] = acc1[r];
        }
    }
    __syncthreads();
    {
        int m = tid >> 4, n = tid & 15;
        float g0 = 0.f, g1 = 0.f;
#pragma unroll
        for (int vv = 0; vv < 4; ++vv) {
            g0 += part[(vv * 2 + 0) * 256 + tid];
            g1 += part[(vv * 2 + 1) * 256 + tid];
        }
        int row = (m >> 2) * HDIM + w * 4 + (m & 3);
        float bias = bih[row] + bhh[row];
        gates[m * 32 + n]      = g0 + bias;
        gates[m * 32 + 16 + n] = g1 + bias;
    }
    __syncthreads();
    if (tid < 128) {
        int hd = tid >> 5, b = tid & 31;
        float gi = gates[(0 * 4 + hd) * 32 + b];
        float gf = gates[(1 * 4 + hd) * 32 + b];
        float gg = gates[(2 * 4 + hd) * 32 + b];
        float go = gates[(3 * 4 + hd) * 32 + b];
        float i_ = 1.f / (1.f + __expf(-gi));
        float f_ = 1.f / (1.f + __expf(-gf));
        float g_ = tanhf(gg);
        float o_ = 1.f / (1.f + __expf(-go));
        int j = w * 4 + hd;
        int cidx = b * HDIM + j;
        float c = f_ * cbuf[cidx] + i_ * g_;
        cbuf[cidx] = c;
        float h = o_ * tanhf(c);
        hs[((size_t)t * BATCH + b) * HDIM + j] = h;
        // broadcast h in B-frag layout for next step (k offset = 1024 + j)
        unsigned short* hn = hfrag + (size_t)((t + 1) & 1) * 32768;
        int kb2   = j >> 5;
        int lane2 = (((j >> 3) & 3) << 4) | (b & 15);
        hn[((kb2 * 2 + (b >> 4)) * 64 + lane2) * 8 + (j & 7)] = f2bf(h);
    }
}

// ---------------------------------------------------------------------------
// Adapter (x + up(relu(down(x)))) + LayerNorm, one WG per (t,b) row.
// If outf != null -> write fp32 to it (final layer -> d_out).
// If xfout != null -> write bf16 B-frag layout (input to next layer).
// ---------------------------------------------------------------------------
__global__ void __launch_bounds__(256) adapter_ln(
    const float* __restrict__ xin,
    const float* __restrict__ Adw, const float* __restrict__ Adb,
    const float* __restrict__ Auw, const float* __restrict__ Aub,
    const float* __restrict__ lng, const float* __restrict__ lnb,
    float* __restrict__ outf, unsigned short* __restrict__ xfout)
{
    __shared__ float xs[1024];
    __shared__ float dsv[DA_DIM];
    __shared__ float red[512];
    int tid = threadIdx.x;
    int row = blockIdx.x;               // t*32 + b
    const float* xr = xin + (size_t)row * HDIM;
    for (int k = tid; k < HDIM; k += 256) xs[k] = xr[k];
    __syncthreads();
    {   // down-proj: d[a] = relu(A_dw[a,:] @ x + A_db[a])
        int a = tid & 63, c4 = tid >> 6;
        const float* wrow = Adw + (size_t)a * HDIM + c4 * 256;
        const float* xx = xs + c4 * 256;
        float p = 0.f;
        for (int k = 0; k < 256; ++k) p += wrow[k] * xx[k];
        red[tid] = p;
    }
    __syncthreads();
    if (tid < DA_DIM) {
        float s = red[tid] + red[64 + tid] + red[128 + tid] + red[192 + tid] + Adb[tid];
        dsv[tid] = s > 0.f ? s : 0.f;
    }
    __syncthreads();
    float y[4]; float s1 = 0.f, s2 = 0.f;
#pragma unroll
    for (int r = 0; r < 4; ++r) {
        int j = tid + 256 * r;
        float acc = xs[j] + Aub[j];
        const float* urow = Auw + (size_t)j * DA_DIM;
#pragma unroll
        for (int a = 0; a < DA_DIM; ++a) acc += urow[a] * dsv[a];
        y[r] = acc; s1 += acc; s2 += acc * acc;
    }
    red[tid] = s1; red[256 + tid] = s2;
    __syncthreads();
    for (int off = 128; off > 0; off >>= 1) {
        if (tid < off) { red[tid] += red[tid + off]; red[256 + tid] += red[256 + tid + off]; }
        __syncthreads();
    }
    float mean = red[0] * (1.f / 1024.f);
    float var  = red[256] * (1.f / 1024.f) - mean * mean;
    float rstd = rsqrtf(var + EPS_LN);
#pragma unroll
    for (int r = 0; r < 4; ++r) {
        int j = tid + 256 * r;
        float o = (y[r] - mean) * rstd * lng[j] + lnb[j];
        if (outf) outf[(size_t)row * HDIM + j] = o;
        if (xfout) {
            int t = row >> 5, b = row & 31;
            int kb = j >> 5;
            int lane2 = (((j >> 3) & 3) << 4) | (b & 15);
            xfout[(size_t)t * 32768 + ((kb * 2 + (b >> 4)) * 64 + lane2) * 8 + (j & 7)] = f2bf(o);
        }
    }
}

extern "C" void kernel_launch(void* const* d_in, const int* in_sizes, int n_in,
                              void* d_out, int out_size, void* d_ws, size_t ws_size,
                              hipStream_t stream)
{
    const float* x   = (const float*)d_in[0];
    const float* Wih = (const float*)d_in[1];
    const float* Whh = (const float*)d_in[2];
    const float* bih = (const float*)d_in[3];
    const float* bhh = (const float*)d_in[4];
    const float* Adw = (const float*)d_in[5];
    const float* Adb = (const float*)d_in[6];
    const float* Auw = (const float*)d_in[7];
    const float* Aub = (const float*)d_in[8];
    const float* lng = (const float*)d_in[9];
    const float* lnb = (const float*)d_in[10];
    float* out = (float*)d_out;

    // workspace carve (~117 MB)
    char* ws = (char*)d_ws;
    unsigned short* wfb = (unsigned short*)ws; ws += (size_t)NWG * 64 * 64 * 8 * 2;       // 16 MB
    unsigned short* xfb = (unsigned short*)ws; ws += (size_t)T_STEPS * 32768 * 2;          // 33.5 MB
    float* hs           = (float*)ws;          ws += (size_t)T_STEPS * BATCH * HDIM * 4;   // 67 MB
    unsigned short* hfr = (unsigned short*)ws; ws += (size_t)2 * 32768 * 2;                // 128 KB
    float* cbuf         = (float*)ws;          ws += (size_t)BATCH * HDIM * 4;             // 128 KB

    hipMemsetAsync(cbuf, 0, (size_t)BATCH * HDIM * 4, stream);
    hipMemsetAsync(hfr, 0, (size_t)2 * 32768 * 2, stream);

    prep_xfrag<<<8192, 256, 0, stream>>>(x, xfb);

    for (int l = 0; l < 2; ++l) {
        prep_wfrag<<<4096, 256, 0, stream>>>(Wih + (size_t)l * GATE4 * HDIM,
                                             Whh + (size_t)l * GATE4 * HDIM, wfb);
        const float* bi = bih + (size_t)l * GATE4;
        const float* bh = bhh + (size_t)l * GATE4;
        for (int t = 0; t < T_STEPS; ++t)
            lstm_step<<<NWG, 256, 0, stream>>>(t, xfb, wfb, hfr, bi, bh, cbuf, hs);

        const float* adw = Adw + (size_t)l * DA_DIM * HDIM;
        const float* adb = Adb + (size_t)l * DA_DIM;
        const float* auw = Auw + (size_t)l * HDIM * DA_DIM;
        const float* aub = Aub + (size_t)l * HDIM;
        const float* lg  = lng + (size_t)l * HDIM;
        const float* lb  = lnb + (size_t)l * HDIM;
        if (l == 0) {
            adapter_ln<<<T_STEPS * BATCH, 256, 0, stream>>>(hs, adw, adb, auw, aub, lg, lb,
                                                            nullptr, xfb);
        } else {
            // raw h_T and c_T of layer 2 (adapter/LN modify x only)
            hipMemcpyAsync(out + 16777216, hs + (size_t)511 * BATCH * HDIM,
                           (size_t)BATCH * HDIM * 4, hipMemcpyDeviceToDevice, stream);
            hipMemcpyAsync(out + 16777216 + 32768, cbuf,
                           (size_t)BATCH * HDIM * 4, hipMemcpyDeviceToDevice, stream);
            adapter_ln<<<T_STEPS * BATCH, 256, 0, stream>>>(hs, adw, adb, auw, aub, lg, lb,
                                                            out, nullptr);
        }
    }
}

// Round 2
// 8603.298 us; speedup vs baseline: 1.2933x; 1.2933x over previous
//
#include <hip/hip_runtime.h>
#include <hip/hip_bf16.h>

typedef __attribute__((ext_vector_type(8))) short short8;
typedef __attribute__((ext_vector_type(4))) float floatx4;
typedef __attribute__((ext_vector_type(4))) int intx4;

#define T_STEPS 512
#define BATCH   32
#define HDIM    1024
#define GATE4   4096
#define DA_DIM  64
#define PWG     128
#define RING    513
#define EPS_LN  1e-5f

// round-to-nearest-even fp32 -> bf16 bit pattern
__device__ __forceinline__ unsigned short f2bf(float f) {
    unsigned u = __float_as_uint(f);
    unsigned r = (u + 0x7FFFu + ((u >> 16) & 1u)) >> 16;
    return (unsigned short)r;
}

// device-coherent (cross-XCD) 16B write-through store: bypasses L1+L2 to IF$
__device__ __forceinline__ void coh_store16(void* p, intx4 v) {
    asm volatile("global_store_dwordx4 %0, %1, off sc0 sc1" :: "v"(p), "v"(v) : "memory");
}
__device__ __forceinline__ void waitcnt_vm0() {
    asm volatile("s_waitcnt vmcnt(0)" ::: "memory");
}

// ---------------------------------------------------------------------------
// W fragment prep: wf[w][mt][kb][lane][j]  (A-operand layout, K=[x;h], 2048)
// w in [0,128): WG id owning h-dims [w*8, w*8+8); mt in {0,1} selects 4 dims.
// m = lane&15 -> row = (m>>2)*1024 + w*8 + mt*4 + (m&3); k = kb*32+(lane>>4)*8+j
// ---------------------------------------------------------------------------
__global__ void __launch_bounds__(256) prep_wfrag(
    const float* __restrict__ Wih, const float* __restrict__ Whh,
    unsigned short* __restrict__ wf)
{
    int gid  = blockIdx.x * 256 + threadIdx.x;   // 4096*256 = 1,048,576
    int lane = gid & 63;
    int kb   = (gid >> 6) & 63;
    int mt   = (gid >> 12) & 1;
    int w    = gid >> 13;                        // 0..127
    int m    = lane & 15;
    int row  = (m >> 2) * HDIM + w * 8 + mt * 4 + (m & 3);
    int k0   = kb * 32 + (lane >> 4) * 8;
    const float* src = (k0 < HDIM) ? (Wih + (size_t)row * HDIM + k0)
                                   : (Whh + (size_t)row * HDIM + (k0 - HDIM));
    unsigned short* dst = wf + (size_t)gid * 8;
#pragma unroll
    for (int j = 0; j < 8; ++j) dst[j] = f2bf(src[j]);
}

// ---------------------------------------------------------------------------
// x fragment prep: per t, xf[t][kb][nb][lane][j]  (B-operand layout)
// n = nb*16 + (lane&15) = batch;  k = kb*32 + (lane>>4)*8 + j
// ---------------------------------------------------------------------------
__global__ void __launch_bounds__(256) prep_xfrag(
    const float* __restrict__ x, unsigned short* __restrict__ xf)
{
    int gid  = blockIdx.x * 256 + threadIdx.x;   // 8192*256 = 2,097,152
    int lane = gid & 63;
    int nb   = (gid >> 6) & 1;
    int kb   = (gid >> 7) & 31;
    int t    = gid >> 12;
    int b    = nb * 16 + (lane & 15);
    int k0   = kb * 32 + (lane >> 4) * 8;
    const float* src = x + ((size_t)(t * BATCH + b)) * HDIM + k0;
    unsigned short* dst = xf + (size_t)t * 32768 + (((kb * 2 + nb) * 64 + lane) * 8);
#pragma unroll
    for (int j = 0; j < 8; ++j) dst[j] = f2bf(src[j]);
}

// ---------------------------------------------------------------------------
// Persistent LSTM layer: 128 WGs x 256 thr, one WG per CU (co-resident).
// WG w owns h-dims [w*8, w*8+8) = 32 gate rows (2 M-tiles). K=2048 fused
// [x_t ; h_{t-1}], split 4 waves x (8 x-kb + 8 h-kb). h broadcast via a
// 513-slot ring (write-once-read-once per launch => no stale-cache hazard),
// write-through sc0sc1 stores + vmcnt(0) before barrier arrival.
// Barrier: 2-level monotonic counters (8 leaves x 16 WGs -> root).
// x-part runs BEFORE the spin-wait to hide barrier propagation.
// ---------------------------------------------------------------------------
__global__ void __launch_bounds__(256, 1) lstm_persistent(
    const unsigned short* __restrict__ xf,
    const unsigned short* __restrict__ wf,
    unsigned short* __restrict__ ring,
    const float* __restrict__ bih, const float* __restrict__ bhh,
    float* __restrict__ cbuf,
    float* __restrict__ hs,
    unsigned* __restrict__ bar,
    int slot0)
{
    __shared__ float part[16 * 256];      // [v][mt*2+nb][m][n]
    __shared__ float gates[2 * 16 * 32];  // [mt][m][batch]
    __shared__ float bias_s[32];          // [mt][m]
    __shared__ intx4 hstage4[32];         // [batch] -> 8 bf16 (one short8)

    unsigned* leaf = bar + (blockIdx.x & 7) * 32;   // 128B-separated lines
    unsigned* root = bar + 8 * 32;

    const int tid  = threadIdx.x;
    const int w    = blockIdx.x;
    const int lane = tid & 63;
    const int v    = tid >> 6;
    const unsigned short* wbase = wf + (size_t)w * 65536;  // 2*64*64*8

    if (tid < 32) {
        int mt = tid >> 4, m = tid & 15;
        int row = (m >> 2) * HDIM + w * 8 + mt * 4 + (m & 3);
        bias_s[tid] = bih[row] + bhh[row];
    }
    const int hd = tid >> 5;          // 0..7 local h-dim
    const int bb = tid & 31;          // batch
    const int j  = w * 8 + hd;        // global h-dim
    float creg = cbuf[bb * HDIM + j]; // c-state lives in a register all launch
    __syncthreads();

    int slot_in = slot0;
    for (int t = 0; t < T_STEPS; ++t) {
        const unsigned short* xb = xf + (size_t)t * 32768;
        floatx4 a00 = {0.f,0.f,0.f,0.f}, a01 = {0.f,0.f,0.f,0.f};
        floatx4 a10 = {0.f,0.f,0.f,0.f}, a11 = {0.f,0.f,0.f,0.f};

        // ---- x-part (independent of h(t-1)) — hides barrier latency ----
#pragma unroll
        for (int i = 0; i < 8; ++i) {
            int kb = v * 8 + i;
            short8 wa0 = *(const short8*)(wbase + (size_t)(kb * 64 + lane) * 8);
            short8 wa1 = *(const short8*)(wbase + (size_t)((64 + kb) * 64 + lane) * 8);
            const unsigned short* xp = xb + (size_t)(kb * 128 + lane) * 8;
            short8 xb0 = *(const short8*)xp;
            short8 xb1 = *(const short8*)(xp + 512);
            a00 = __builtin_amdgcn_mfma_f32_16x16x32_bf16(wa0, xb0, a00, 0, 0, 0);
            a01 = __builtin_amdgcn_mfma_f32_16x16x32_bf16(wa0, xb1, a01, 0, 0, 0);
            a10 = __builtin_amdgcn_mfma_f32_16x16x32_bf16(wa1, xb0, a10, 0, 0, 0);
            a11 = __builtin_amdgcn_mfma_f32_16x16x32_bf16(wa1, xb1, a11, 0, 0, 0);
        }

        // ---- wait for all WGs to have published h(t-1) ----
        if (tid == 0) {
            unsigned tgt = (unsigned)t * 8u;
            while (__hip_atomic_load(root, __ATOMIC_RELAXED, __HIP_MEMORY_SCOPE_AGENT) < tgt)
                __builtin_amdgcn_s_sleep(1);
        }
        __syncthreads();

        // ---- h-part: plain loads (ring slot is cold in L2 => fresh from IF$) ----
        const unsigned short* rb = ring + (size_t)slot_in * 32768;
#pragma unroll
        for (int i = 0; i < 8; ++i) {
            int kh = v * 8 + i;
            short8 wa0 = *(const short8*)(wbase + (size_t)((32 + kh) * 64 + lane) * 8);
            short8 wa1 = *(const short8*)(wbase + (size_t)((96 + kh) * 64 + lane) * 8);
            const unsigned short* hp = rb + (size_t)(kh * 128 + lane) * 8;
            short8 hb0 = *(const short8*)hp;
            short8 hb1 = *(const short8*)(hp + 512);
            a00 = __builtin_amdgcn_mfma_f32_16x16x32_bf16(wa0, hb0, a00, 0, 0, 0);
            a01 = __builtin_amdgcn_mfma_f32_16x16x32_bf16(wa0, hb1, a01, 0, 0, 0);
            a10 = __builtin_amdgcn_mfma_f32_16x16x32_bf16(wa1, hb0, a10, 0, 0, 0);
            a11 = __builtin_amdgcn_mfma_f32_16x16x32_bf16(wa1, hb1, a11, 0, 0, 0);
        }

        // ---- cross-wave K reduction via LDS ----
        {
            int n = lane & 15, q = lane >> 4;
#pragma unroll
            for (int r = 0; r < 4; ++r) {
                int m16 = (q * 4 + r) * 16 + n;
                part[(v * 4 + 0) * 256 + m16] = a00[r];
                part[(v * 4 + 1) * 256 + m16] = a01[r];
                part[(v * 4 + 2) * 256 + m16] = a10[r];
                part[(v * 4 + 3) * 256 + m16] = a11[r];
            }
        }
        __syncthreads();
        {
            int m = tid >> 4, n = tid & 15;
            int m16 = m * 16 + n;
#pragma unroll
            for (int mt = 0; mt < 2; ++mt)
#pragma unroll
                for (int nb = 0; nb < 2; ++nb) {
                    int c = mt * 2 + nb;
                    float g = part[(0 * 4 + c) * 256 + m16]
                            + part[(1 * 4 + c) * 256 + m16]
                            + part[(2 * 4 + c) * 256 + m16]
                            + part[(3 * 4 + c) * 256 + m16];
                    gates[(mt * 16 + m) * 32 + nb * 16 + n] = g + bias_s[mt * 16 + m];
                }
        }
        __syncthreads();

        // ---- gate nonlinearities + c/h update (all 256 threads) ----
        {
            int r3 = hd & 3, mt = hd >> 2;
            float gi = gates[(mt * 16 +  0 + r3) * 32 + bb];
            float gf = gates[(mt * 16 +  4 + r3) * 32 + bb];
            float gg = gates[(mt * 16 +  8 + r3) * 32 + bb];
            float go = gates[(mt * 16 + 12 + r3) * 32 + bb];
            float i_ = 1.f / (1.f + __expf(-gi));
            float f_ = 1.f / (1.f + __expf(-gf));
            float g_ = tanhf(gg);
            float o_ = 1.f / (1.f + __expf(-go));
            creg = f_ * creg + i_ * g_;
            float h = o_ * tanhf(creg);
            hs[((size_t)t * BATCH + bb) * HDIM + j] = h;
            ((unsigned short*)&hstage4[bb])[hd] = f2bf(h);
        }
        __syncthreads();

        // ---- publish h(t): one 16B write-through store per batch ----
        int slot_out = (slot_in + 1 == RING) ? 0 : slot_in + 1;
        if (tid < 32) {
            unsigned short* hn = ring + (size_t)slot_out * 32768;
            int kb2   = w >> 2;
            int lane2 = ((w & 3) << 4) | (tid & 15);
            unsigned short* dst = hn + (size_t)((kb2 * 2 + (tid >> 4)) * 64 + lane2) * 8;
            coh_store16(dst, hstage4[tid]);
        }
        waitcnt_vm0();   // h stores globally visible before arrival
        if (tid == 0) {
            unsigned a = __hip_atomic_fetch_add(leaf, 1u, __ATOMIC_RELAXED,
                                                __HIP_MEMORY_SCOPE_AGENT);
            if (a + 1u == (unsigned)(t + 1) * 16u)
                __hip_atomic_fetch_add(root, 1u, __ATOMIC_RELAXED,
                                       __HIP_MEMORY_SCOPE_AGENT);
        }
        slot_in = slot_out;
    }
    cbuf[bb * HDIM + j] = creg;
}

// ---------------------------------------------------------------------------
// Adapter (x + up(relu(down(x)))) + LayerNorm, one WG per (t,b) row.
// In-place safe: row fully staged to LDS before any global write.
// ---------------------------------------------------------------------------
__global__ void __launch_bounds__(256) adapter_ln(
    const float* __restrict__ xin,
    const float* __restrict__ Adw, const float* __restrict__ Adb,
    const float* __restrict__ Auw, const float* __restrict__ Aub,
    const float* __restrict__ lng, const float* __restrict__ lnb,
    float* __restrict__ outf, unsigned short* __restrict__ xfout)
{
    __shared__ float xs[1024];
    __shared__ float dsv[DA_DIM];
    __shared__ float red[512];
    int tid = threadIdx.x;
    int row = blockIdx.x;               // t*32 + b
    const float* xr = xin + (size_t)row * HDIM;
    for (int k = tid; k < HDIM; k += 256) xs[k] = xr[k];
    __syncthreads();
    {   // down-proj: d[a] = relu(A_dw[a,:] @ x + A_db[a])
        int a = tid & 63, c4 = tid >> 6;
        const float* wrow = Adw + (size_t)a * HDIM + c4 * 256;
        const float* xx = xs + c4 * 256;
        float p = 0.f;
        for (int k = 0; k < 256; ++k) p += wrow[k] * xx[k];
        red[tid] = p;
    }
    __syncthreads();
    if (tid < DA_DIM) {
        float s = red[tid] + red[64 + tid] + red[128 + tid] + red[192 + tid] + Adb[tid];
        dsv[tid] = s > 0.f ? s : 0.f;
    }
    __syncthreads();
    float y[4]; float s1 = 0.f, s2 = 0.f;
#pragma unroll
    for (int r = 0; r < 4; ++r) {
        int jj = tid + 256 * r;
        float acc = xs[jj] + Aub[jj];
        const float* urow = Auw + (size_t)jj * DA_DIM;
#pragma unroll
        for (int a = 0; a < DA_DIM; ++a) acc += urow[a] * dsv[a];
        y[r] = acc; s1 += acc; s2 += acc * acc;
    }
    red[tid] = s1; red[256 + tid] = s2;
    __syncthreads();
    for (int off = 128; off > 0; off >>= 1) {
        if (tid < off) { red[tid] += red[tid + off]; red[256 + tid] += red[256 + tid + off]; }
        __syncthreads();
    }
    float mean = red[0] * (1.f / 1024.f);
    float var  = red[256] * (1.f / 1024.f) - mean * mean;
    float rstd = rsqrtf(var + EPS_LN);
#pragma unroll
    for (int r = 0; r < 4; ++r) {
        int jj = tid + 256 * r;
        float o = (y[r] - mean) * rstd * lng[jj] + lnb[jj];
        if (outf) outf[(size_t)row * HDIM + jj] = o;
        if (xfout) {
            int t = row >> 5, b = row & 31;
            int kb = jj >> 5;
            int lane2 = (((jj >> 3) & 3) << 4) | (b & 15);
            xfout[(size_t)t * 32768 + ((kb * 2 + (b >> 4)) * 64 + lane2) * 8 + (jj & 7)] = f2bf(o);
        }
    }
}

extern "C" void kernel_launch(void* const* d_in, const int* in_sizes, int n_in,
                              void* d_out, int out_size, void* d_ws, size_t ws_size,
                              hipStream_t stream)
{
    const float* x   = (const float*)d_in[0];
    const float* Wih = (const float*)d_in[1];
    const float* Whh = (const float*)d_in[2];
    const float* bih = (const float*)d_in[3];
    const float* bhh = (const float*)d_in[4];
    const float* Adw = (const float*)d_in[5];
    const float* Adb = (const float*)d_in[6];
    const float* Auw = (const float*)d_in[7];
    const float* Aub = (const float*)d_in[8];
    const float* lng = (const float*)d_in[9];
    const float* lnb = (const float*)d_in[10];
    float* out = (float*)d_out;

    // workspace carve (~84 MB)
    char* ws = (char*)d_ws;
    unsigned short* wfb  = (unsigned short*)ws; ws += (size_t)GATE4 * 2048 * 2;      // 16.78 MB
    unsigned short* xfb  = (unsigned short*)ws; ws += (size_t)T_STEPS * 32768 * 2;   // 33.55 MB
    unsigned short* ring = (unsigned short*)ws; ws += (size_t)RING * 32768 * 2;      // 33.62 MB
    float*    cbuf = (float*)ws;    ws += (size_t)BATCH * HDIM * 4;                  // 128 KB
    unsigned* bar  = (unsigned*)ws; ws += 2048;
    float* hs = out;   // alias hs onto d_out x-region (adapter is in-place safe)

    hipMemsetAsync(cbuf, 0, (size_t)BATCH * HDIM * 4, stream);
    hipMemsetAsync(ring, 0, 32768 * 2, stream);     // ring slot 0 = h0 = 0
    hipMemsetAsync(bar, 0, 2048, stream);

    prep_xfrag<<<8192, 256, 0, stream>>>(x, xfb);

    for (int l = 0; l < 2; ++l) {
        prep_wfrag<<<4096, 256, 0, stream>>>(Wih + (size_t)l * GATE4 * HDIM,
                                             Whh + (size_t)l * GATE4 * HDIM, wfb);
        if (l == 1) hipMemsetAsync(bar, 0, 2048, stream);
        lstm_persistent<<<PWG, 256, 0, stream>>>(xfb, wfb, ring,
                                                 bih + (size_t)l * GATE4,
                                                 bhh + (size_t)l * GATE4,
                                                 cbuf, hs, bar, l * T_STEPS);

        const float* adw = Adw + (size_t)l * DA_DIM * HDIM;
        const float* adb = Adb + (size_t)l * DA_DIM;
        const float* auw = Auw + (size_t)l * HDIM * DA_DIM;
        const float* aub = Aub + (size_t)l * HDIM;
        const float* lg  = lng + (size_t)l * HDIM;
        const float* lb  = lnb + (size_t)l * HDIM;
        if (l == 0) {
            adapter_ln<<<T_STEPS * BATCH, 256, 0, stream>>>(hs, adw, adb, auw, aub, lg, lb,
                                                            nullptr, xfb);
        } else {
            // raw h_T (hs row 511) and c_T before adapter overwrites rows in place
            hipMemcpyAsync(out + 16777216, hs + (size_t)511 * BATCH * HDIM,
                           (size_t)BATCH * HDIM * 4, hipMemcpyDeviceToDevice, stream);
            hipMemcpyAsync(out + 16777216 + 32768, cbuf,
                           (size_t)BATCH * HDIM * 4, hipMemcpyDeviceToDevice, stream);
            adapter_ln<<<T_STEPS * BATCH, 256, 0, stream>>>(hs, adw, adb, auw, aub, lg, lb,
                                                            out, nullptr);
        }
    }
}